// Round 10
// baseline (368.890 us; speedup 1.0000x reference)
//
#include <hip/hip_runtime.h>
#include <hip/hip_bf16.h>
#include <math.h>

// GAT 2-layer. Round 10: histogram contention fix — 16-way replicated,
// line-padded degree counters (degR[d*16+r], r=(e>>8)&15): ~16 atomics per
// 64B line instead of ~256. kscan1 folds replicas (node total -> rowptr,
// in-place exclusive replica prefix -> repoff). h1b stores remapped to full
// 256B-contiguous rows per instruction. Rest as R9.

typedef unsigned short u16;
typedef unsigned int u32;
typedef __attribute__((ext_vector_type(8))) short bf16x8;
typedef __attribute__((ext_vector_type(4))) float f32x4;

__device__ __forceinline__ float eluf(float v) { return v > 0.f ? v : expm1f(v); }
__device__ __forceinline__ u16 f2bf(float f) {
    u32 u = __float_as_uint(f);
    u += 0x7fff + ((u >> 16) & 1);          // RNE
    return (u16)(u >> 16);
}
__device__ __forceinline__ float bf2f(u16 u) {
    return __uint_as_float(((u32)u) << 16);
}
// exp(leaky02(e)) = exp2(e * (e>=0 ? log2e : 0.2*log2e))
__device__ __forceinline__ float expleaky(float e) {
    float m = e >= 0.f ? 1.44269504f : 0.28853901f;
    return exp2f(e * m);
}

// ---------------- ksetup: W1 frag swizzle | W2 prep | degR zero ------------
__global__ __launch_bounds__(256) void ksetup(
    const float* __restrict__ W1, const float* __restrict__ W2,
    const float* __restrict__ ats2, const float* __restrict__ atd2,
    u16* __restrict__ w1fh, u16* __restrict__ w1fl,
    float* __restrict__ u, float* __restrict__ v, u16* __restrict__ w2tb,
    int* __restrict__ degR, int N)
{
    const int b = blockIdx.x, tid = threadIdx.x;
    if (b < 64) {
        int idx = b * 256 + tid;
        int j = idx & 7, l = (idx >> 3) & 63, q = (idx >> 9) & 3, ct = idx >> 11;
        int k = q * 32 + (l >> 4) * 8 + j;
        int n = ct * 16 + (l & 15);
        float w = W1[k * 128 + n];
        u16 hv = f2bf(w);
        w1fh[idx] = hv;
        w1fl[idx] = f2bf(w - bf2f(hv));
    } else if (b == 64) {
        if (tid < 128) {
            float su = 0.f, sv = 0.f;
            #pragma unroll
            for (int j = 0; j < 16; ++j) {
                float w = W2[tid * 16 + j];
                su = fmaf(w, ats2[j], su);
                sv = fmaf(w, atd2[j], sv);
                w2tb[j * 128 + tid] = f2bf(w);
            }
            u[tid] = su; v[tid] = sv;
        }
    } else {
        int z = (b - 65) * 1024 + tid * 4;
        if (z < N * 16) *(int4*)&degR[z] = make_int4(0, 0, 0, 0);
    }
}

// ---------------- mega1: khist prologue + MFMA hi/lo GEMM ------------------
#define REPSTRIDE 136   // u16 per row (272 B)
__global__ __launch_bounds__(256) void mega1(
    const float* __restrict__ x, const u16* __restrict__ w1fh,
    const u16* __restrict__ w1fl,
    const float* __restrict__ att_s, const float* __restrict__ att_d,
    u16* __restrict__ h1b, float* __restrict__ as1, float* __restrict__ ad1,
    int N,
    const int* __restrict__ ei, int* __restrict__ degR, int* __restrict__ rank,
    int E, int grid)
{
    __shared__ union {
        struct { u16 lh[8192]; u16 ll[8192]; } w;
        u16 rep[16384];
    } sm;
    const int tid = threadIdx.x;

    // --- khist: 16-way replicated counters, 4 independent atomic slots ---
    {
        const int st = grid * 256;
        const int e0 = blockIdx.x * 256 + tid;
        const int ea = e0, eb = e0 + st, ec = e0 + 2 * st, ed = e0 + 3 * st;
        int da = (ea < E) ? ei[E + ea] : -1;
        int db = (eb < E) ? ei[E + eb] : -1;
        int dc = (ec < E) ? ei[E + ec] : -1;
        int dd = (ed < E) ? ei[E + ed] : -1;
        int ra = 0, rb = 0, rc = 0, rd = 0;
        if (da >= 0) ra = atomicAdd(&degR[da * 16 + ((ea >> 8) & 15)], 1);
        if (db >= 0) rb = atomicAdd(&degR[db * 16 + ((eb >> 8) & 15)], 1);
        if (dc >= 0) rc = atomicAdd(&degR[dc * 16 + ((ec >> 8) & 15)], 1);
        if (dd >= 0) rd = atomicAdd(&degR[dd * 16 + ((ed >> 8) & 15)], 1);
        if (da >= 0) rank[ea] = ra;
        if (db >= 0) rank[eb] = rb;
        if (dc >= 0) rank[ec] = rc;
        if (dd >= 0) rank[ed] = rd;
        for (int e = e0 + 4 * st; e < E; e += st) {   // safety tail
            int d2 = ei[E + e];
            rank[e] = atomicAdd(&degR[d2 * 16 + ((e >> 8) & 15)], 1);
        }
    }

    const int wv = tid >> 6, lane = tid & 63;
    const int base = blockIdx.x * 64 + wv * 16;
    const int m = lane & 15, quad = lane >> 4;

    int arow = base + m;
    if (arow >= N) arow = 0;
    const float* xr = &x[(size_t)arow * 128 + quad * 8];
    bf16x8 ah[4], al[4];
    #pragma unroll
    for (int q = 0; q < 4; ++q) {
        float4 f0 = *(const float4*)&xr[q * 32];
        float4 f1 = *(const float4*)&xr[q * 32 + 4];
        float fv[8] = {f0.x, f0.y, f0.z, f0.w, f1.x, f1.y, f1.z, f1.w};
        union { u16 us[8]; bf16x8 v; } hh, lu;
        #pragma unroll
        for (int j = 0; j < 8; ++j) {
            u16 h = f2bf(fv[j]);
            hh.us[j] = h;
            lu.us[j] = f2bf(fv[j] - bf2f(h));
        }
        ah[q] = hh.v; al[q] = lu.v;
    }

    f32x4 accs[8];
    for (int p = 0; p < 2; ++p) {
        __syncthreads();
        #pragma unroll
        for (int i = 0; i < 4; ++i) {
            int fi = (tid + i * 256) * 8;
            *(uint4*)&sm.w.lh[fi] = *(const uint4*)&w1fh[p * 8192 + fi];
            *(uint4*)&sm.w.ll[fi] = *(const uint4*)&w1fl[p * 8192 + fi];
        }
        __syncthreads();
        #pragma unroll
        for (int ctl = 0; ctl < 4; ++ctl) {
            f32x4 acc = {0.f, 0.f, 0.f, 0.f};
            #pragma unroll
            for (int q = 0; q < 4; ++q) {
                const int off = ((ctl * 4 + q) * 64 + lane) * 8;
                bf16x8 bh = *(const bf16x8*)&sm.w.lh[off];
                bf16x8 bl = *(const bf16x8*)&sm.w.ll[off];
                acc = __builtin_amdgcn_mfma_f32_16x16x32_bf16(ah[q], bh, acc, 0, 0, 0);
                acc = __builtin_amdgcn_mfma_f32_16x16x32_bf16(al[q], bh, acc, 0, 0, 0);
                acc = __builtin_amdgcn_mfma_f32_16x16x32_bf16(ah[q], bl, acc, 0, 0, 0);
            }
            accs[p * 4 + ctl] = acc;
        }
    }

    // attention dots
    #pragma unroll
    for (int h = 0; h < 4; ++h) {
        const float cs0 = att_s[h * 32 + m];
        const float cs1 = att_s[h * 32 + 16 + m];
        const float cd0 = att_d[h * 32 + m];
        const float cd1 = att_d[h * 32 + 16 + m];
        float sp[4], dp[4];
        #pragma unroll
        for (int r = 0; r < 4; ++r) {
            sp[r] = fmaf(accs[2 * h][r], cs0, accs[2 * h + 1][r] * cs1);
            dp[r] = fmaf(accs[2 * h][r], cd0, accs[2 * h + 1][r] * cd1);
        }
        #pragma unroll
        for (int r = 0; r < 4; ++r) {
            sp[r] += __shfl_xor(sp[r], 1); sp[r] += __shfl_xor(sp[r], 2);
            sp[r] += __shfl_xor(sp[r], 4); sp[r] += __shfl_xor(sp[r], 8);
            dp[r] += __shfl_xor(dp[r], 1); dp[r] += __shfl_xor(dp[r], 2);
            dp[r] += __shfl_xor(dp[r], 4); dp[r] += __shfl_xor(dp[r], 8);
        }
        if (m == 0) {
            #pragma unroll
            for (int r = 0; r < 4; ++r) {
                int rr = base + quad * 4 + r;
                if (rr < N) {
                    as1[rr * 4 + h] = sp[r];
                    ad1[rr * 4 + h] = dp[r];
                }
            }
        }
    }

    // repack -> full-row contiguous h1b stores (16 lanes = one 256B row)
    __syncthreads();
    u16* rep = sm.rep + wv * (16 * REPSTRIDE);
    #pragma unroll
    for (int ct = 0; ct < 8; ++ct) {
        #pragma unroll
        for (int r = 0; r < 4; ++r)
            rep[(quad * 4 + r) * REPSTRIDE + ct * 16 + m] = f2bf(accs[ct][r]);
    }
    const int chunk = lane & 15;
    #pragma unroll
    for (int round = 0; round < 4; ++round) {
        int row = round * 4 + (lane >> 4);
        uint4 vv = *(const uint4*)&rep[row * REPSTRIDE + chunk * 8];
        int grow = base + row;
        if (grow < N)
            *(uint4*)&h1b[(size_t)grow * 128 + chunk * 8] = vv;
    }
}

// ---------------- kscan1: fold replicas, rowptr + in-place repoff ----------
__global__ __launch_bounds__(256) void kscan1(
    int* __restrict__ degR, int* __restrict__ rowptr,
    int* __restrict__ bsum, int N)
{
    __shared__ int lds[256];
    const int t = threadIdx.x;
    const int base = blockIdx.x * 1024 + t * 4;
    int tot[4];
    int s = 0;
    #pragma unroll
    for (int j = 0; j < 4; ++j) {
        int node = base + j;
        int sum = 0;
        if (node < N) {
            int4 c[4];
            #pragma unroll
            for (int q = 0; q < 4; ++q) c[q] = *(int4*)&degR[node * 16 + q * 4];
            int vals[16] = {c[0].x, c[0].y, c[0].z, c[0].w,
                            c[1].x, c[1].y, c[1].z, c[1].w,
                            c[2].x, c[2].y, c[2].z, c[2].w,
                            c[3].x, c[3].y, c[3].z, c[3].w};
            int run = 0;
            #pragma unroll
            for (int q = 0; q < 16; ++q) { int cv = vals[q]; vals[q] = run; run += cv; }
            sum = run;
            #pragma unroll
            for (int q = 0; q < 4; ++q) {
                int4 pv = {vals[q * 4], vals[q * 4 + 1], vals[q * 4 + 2], vals[q * 4 + 3]};
                *(int4*)&degR[node * 16 + q * 4] = pv;
            }
        }
        tot[j] = sum; s += sum;
    }
    lds[t] = s;
    __syncthreads();
    for (int off = 1; off < 256; off <<= 1) {
        int y = (t >= off) ? lds[t - off] : 0;
        __syncthreads();
        lds[t] += y;
        __syncthreads();
    }
    int run = lds[t] - s;
    #pragma unroll
    for (int j = 0; j < 4; ++j) {
        if (base + j < N) rowptr[base + j] = run;
        run += tot[j];
    }
    if (t == 255) bsum[blockIdx.x] = lds[255];
}

__global__ __launch_bounds__(128) void kscan2(int* __restrict__ bsum, int NB)
{
    __shared__ int lds[128];
    const int t = threadIdx.x;
    int v = (t < NB) ? bsum[t] : 0;
    lds[t] = v;
    __syncthreads();
    for (int off = 1; off < 128; off <<= 1) {
        int y = (t >= off) ? lds[t - off] : 0;
        __syncthreads();
        lds[t] += y;
        __syncthreads();
    }
    if (t < NB) bsum[t] = lds[t] - v;
}

// ---------------- kscat: scatter with replica offsets ----------------------
__global__ __launch_bounds__(256) void kscat(
    const int* __restrict__ ei, const int* __restrict__ rowptr,
    const int* __restrict__ bsum, const int* __restrict__ rank,
    const int* __restrict__ degR, int* __restrict__ colidx, int E)
{
    int e = blockIdx.x * 256 + threadIdx.x;
    if (e >= E) return;
    int s = ei[e], d = ei[E + e];
    int r = (e >> 8) & 15;
    colidx[rowptr[d] + bsum[d >> 10] + degR[d * 16 + r] + rank[e]] = s;
}

// ---------------- KG1: layer-1 gather, in-wave weights ---------------------
__global__ __launch_bounds__(256) void kg1(
    const int* __restrict__ rowptr, const int* __restrict__ bsum,
    const int* __restrict__ colidx,
    const u16* __restrict__ h1b, const float* __restrict__ as1,
    const float* __restrict__ ad1, const float* __restrict__ b1,
    const float* __restrict__ u, const float* __restrict__ v,
    u16* __restrict__ x2b, float* __restrict__ as2, float* __restrict__ ad2,
    int N, int E)
{
    const int d = blockIdx.x * 4 + (threadIdx.x >> 6);
    if (d >= N) return;
    const int lane = threadIdx.x & 63;
    const int c = lane * 2;
    const int headB = lane >> 4;
    const int headA = lane & 3;
    const int eA = lane >> 2;

    const float adA = ad1[d * 4 + headA];
    const float wself = expleaky(as1[d * 4 + headB] + ad1[d * 4 + headB]);
    u32 hd = *(const u32*)&h1b[(d << 7) + c];
    float accx = wself * bf2f((u16)hd);
    float accy = wself * bf2f((u16)(hd >> 16));
    float den = wself;

    int i0r = rowptr[d] + bsum[d >> 10];
    int i1r = (d + 1 == N) ? E : rowptr[d + 1] + bsum[(d + 1) >> 10];
    const int i0 = __builtin_amdgcn_readfirstlane(i0r);
    const int i1 = __builtin_amdgcn_readfirstlane(i1r);

    for (int i = i0; i < i1; i += 16) {
        const int nb = min(16, i1 - i);
        const int ii = i + eA;
        const int iic = ii < i1 ? ii : i0;
        int sAv = colidx[iic];
        float wA = expleaky(as1[(sAv << 2) + headA] + adA);
        wA = (ii < i1) ? wA : 0.f;
        int e = 0;
        for (; e + 8 <= nb; e += 8) {
            int s0 = colidx[i + e + 0];
            int s1 = colidx[i + e + 1];
            int s2 = colidx[i + e + 2];
            int s3 = colidx[i + e + 3];
            int s4 = colidx[i + e + 4];
            int s5 = colidx[i + e + 5];
            int s6 = colidx[i + e + 6];
            int s7 = colidx[i + e + 7];
            float w0 = __shfl(wA, ((e + 0) << 2) + headB);
            float w1 = __shfl(wA, ((e + 1) << 2) + headB);
            float w2 = __shfl(wA, ((e + 2) << 2) + headB);
            float w3 = __shfl(wA, ((e + 3) << 2) + headB);
            float w4 = __shfl(wA, ((e + 4) << 2) + headB);
            float w5 = __shfl(wA, ((e + 5) << 2) + headB);
            float w6 = __shfl(wA, ((e + 6) << 2) + headB);
            float w7 = __shfl(wA, ((e + 7) << 2) + headB);
            u32 v0 = *(const u32*)&h1b[(s0 << 7) + c];
            u32 v1 = *(const u32*)&h1b[(s1 << 7) + c];
            u32 v2 = *(const u32*)&h1b[(s2 << 7) + c];
            u32 v3 = *(const u32*)&h1b[(s3 << 7) + c];
            u32 v4 = *(const u32*)&h1b[(s4 << 7) + c];
            u32 v5 = *(const u32*)&h1b[(s5 << 7) + c];
            u32 v6 = *(const u32*)&h1b[(s6 << 7) + c];
            u32 v7 = *(const u32*)&h1b[(s7 << 7) + c];
            accx = fmaf(w0, bf2f((u16)v0), accx); accy = fmaf(w0, bf2f((u16)(v0 >> 16)), accy);
            accx = fmaf(w1, bf2f((u16)v1), accx); accy = fmaf(w1, bf2f((u16)(v1 >> 16)), accy);
            accx = fmaf(w2, bf2f((u16)v2), accx); accy = fmaf(w2, bf2f((u16)(v2 >> 16)), accy);
            accx = fmaf(w3, bf2f((u16)v3), accx); accy = fmaf(w3, bf2f((u16)(v3 >> 16)), accy);
            accx = fmaf(w4, bf2f((u16)v4), accx); accy = fmaf(w4, bf2f((u16)(v4 >> 16)), accy);
            accx = fmaf(w5, bf2f((u16)v5), accx); accy = fmaf(w5, bf2f((u16)(v5 >> 16)), accy);
            accx = fmaf(w6, bf2f((u16)v6), accx); accy = fmaf(w6, bf2f((u16)(v6 >> 16)), accy);
            accx = fmaf(w7, bf2f((u16)v7), accx); accy = fmaf(w7, bf2f((u16)(v7 >> 16)), accy);
            den += ((w0 + w1) + (w2 + w3)) + ((w4 + w5) + (w6 + w7));
        }
        for (; e < nb; ++e) {
            int s = colidx[i + e];
            float w = __shfl(wA, (e << 2) + headB);
            u32 hv = *(const u32*)&h1b[(s << 7) + c];
            accx = fmaf(w, bf2f((u16)hv), accx);
            accy = fmaf(w, bf2f((u16)(hv >> 16)), accy);
            den += w;
        }
    }

    const float inv = 1.f / den;
    const float2 bv = *(const float2*)&b1[c];
    const float x2a = eluf(fmaf(accx, inv, bv.x));
    const float x2c = eluf(fmaf(accy, inv, bv.y));

    u32 pk = ((u32)f2bf(x2c) << 16) | (u32)f2bf(x2a);
    *(u32*)&x2b[(d << 7) + c] = pk;

    const float2 uv = *(const float2*)&u[c];
    const float2 vv = *(const float2*)&v[c];
    float sA = fmaf(x2a, uv.x, x2c * uv.y);
    float sB = fmaf(x2a, vv.x, x2c * vv.y);
    #pragma unroll
    for (int m = 1; m < 64; m <<= 1) {
        sA += __shfl_xor(sA, m);
        sB += __shfl_xor(sB, m);
    }
    if (lane == 0) { as2[d] = sA; ad2[d] = sB; }
}

// ---------------- KH2: h2 = x2 @ W2 via MFMA (bf16 out) --------------------
__global__ __launch_bounds__(256) void kh2(
    const u16* __restrict__ x2b, const u16* __restrict__ w2tb,
    u16* __restrict__ h2b, int N)
{
    const int wv = threadIdx.x >> 6, lane = threadIdx.x & 63;
    const int n0 = blockIdx.x * 64 + wv * 16;
    if (n0 >= N) return;
    const int m = lane & 15;
    const int kq = lane >> 4;
    bf16x8 bfr[4];
    #pragma unroll
    for (int q = 0; q < 4; ++q)
        bfr[q] = *(const bf16x8*)&w2tb[m * 128 + q * 32 + kq * 8];

    int ar = n0 + m;
    if (ar >= N) ar = N - 1;
    const u16* arow = &x2b[((size_t)ar << 7) + kq * 8];
    f32x4 acc = {0.f, 0.f, 0.f, 0.f};
    #pragma unroll
    for (int q = 0; q < 4; ++q) {
        bf16x8 af = *(const bf16x8*)&arow[q * 32];
        acc = __builtin_amdgcn_mfma_f32_16x16x32_bf16(af, bfr[q], acc, 0, 0, 0);
    }
    #pragma unroll
    for (int r = 0; r < 4; ++r) {
        int rr = n0 + kq * 4 + r;
        if (rr < N) h2b[((size_t)rr << 4) + m] = f2bf(acc[r]);
    }
}

// ---------------- KG2: layer-2 gather, in-wave weights ---------------------
__global__ __launch_bounds__(256) void kg2(
    const int* __restrict__ rowptr, const int* __restrict__ bsum,
    const int* __restrict__ colidx,
    const u16* __restrict__ h2b, const float* __restrict__ as2,
    const float* __restrict__ ad2, const float* __restrict__ b2,
    float* __restrict__ out, int N, int E)
{
    const int d = blockIdx.x * 4 + (threadIdx.x >> 6);
    if (d >= N) return;
    const int lane = threadIdx.x & 63;
    const int ch = lane & 7, g = lane >> 3;

    const float ad_d = ad2[d];
    float acc0 = 0.f, acc1 = 0.f, den = 0.f;
    int i0r = rowptr[d] + bsum[d >> 10];
    int i1r = (d + 1 == N) ? E : rowptr[d + 1] + bsum[(d + 1) >> 10];
    const int i0 = __builtin_amdgcn_readfirstlane(i0r);
    const int i1 = __builtin_amdgcn_readfirstlane(i1r);

    for (int i = i0; i < i1; i += 64) {
        const int nb = min(64, i1 - i);
        const int idx = i + lane;
        const int idxc = idx < i1 ? idx : i0;
        int sA = colidx[idxc];
        float wA = expleaky(as2[sA] + ad_d);
        wA = (idx < i1) ? wA : 0.f;
        const int kU = (nb + 7) >> 3;
        for (int k = 0; k < kU; ++k) {
            int e = g + 8 * k;
            int ec = e < nb ? e : 0;
            float w = __shfl(wA, ec);
            int s = __shfl(sA, ec);
            if (e >= nb) w = 0.f;
            u32 hv = *(const u32*)&h2b[(s << 4) + ch * 2];
            acc0 = fmaf(w, bf2f((u16)hv), acc0);
            acc1 = fmaf(w, bf2f((u16)(hv >> 16)), acc1);
            den += w;
        }
    }
    acc0 += __shfl_xor(acc0, 8); acc0 += __shfl_xor(acc0, 16); acc0 += __shfl_xor(acc0, 32);
    acc1 += __shfl_xor(acc1, 8); acc1 += __shfl_xor(acc1, 16); acc1 += __shfl_xor(acc1, 32);
    den  += __shfl_xor(den, 8);  den  += __shfl_xor(den, 16);  den  += __shfl_xor(den, 32);

    const float wself = expleaky(as2[d] + ad_d);
    u32 hd = *(const u32*)&h2b[(d << 4) + ch * 2];
    acc0 = fmaf(wself, bf2f((u16)hd), acc0);
    acc1 = fmaf(wself, bf2f((u16)(hd >> 16)), acc1);
    den += wself;
    if (g == 0) {
        float2 ov = {acc0 / den + b2[ch * 2], acc1 / den + b2[ch * 2 + 1]};
        *(float2*)&out[(d << 4) + ch * 2] = ov;
    }
}

extern "C" void kernel_launch(void* const* d_in, const int* in_sizes, int n_in,
                              void* d_out, int out_size, void* d_ws, size_t ws_size,
                              hipStream_t stream) {
    const float* x    = (const float*)d_in[0];
    const int*   ei   = (const int*)d_in[1];
    const float* W1   = (const float*)d_in[2];
    const float* ats1 = (const float*)d_in[3];
    const float* atd1 = (const float*)d_in[4];
    const float* b1   = (const float*)d_in[5];
    const float* W2   = (const float*)d_in[6];
    const float* ats2 = (const float*)d_in[7];
    const float* atd2 = (const float*)d_in[8];
    const float* b2   = (const float*)d_in[9];
    float* out = (float*)d_out;
    const int N = in_sizes[0] / 128;
    const int E = in_sizes[1] / 2;

    u16* h1b   = (u16*)d_ws;                        // 128N
    u16* x2b   = h1b + (size_t)N * 128;             // 128N
    u16* h2b   = x2b + (size_t)N * 128;             // 16N
    u16* w2tb  = h2b + (size_t)N * 16;              // 2048
    u16* w1fh  = w2tb + 2048;                       // 16384
    u16* w1fl  = w1fh + 16384;                      // 16384
    float* as1 = (float*)(w1fl + 16384);            // 4N
    float* ad1 = as1 + (size_t)N * 4;               // 4N
    float* as2 = ad1 + (size_t)N * 4;               // N
    float* ad2 = as2 + N;                           // N
    float* u   = ad2 + N;                           // 128
    float* v   = u + 128;                           // 128
    int* degR   = (int*)(v + 128);                  // 16N (64B/node)
    int* rowptr = degR + (size_t)N * 16;            // N+1 (padded)
    int* bsum   = rowptr + ((N + 7) & ~3);          // 128
    int* colidx = bsum + 128;                       // E
    int* rank   = colidx + E;                       // E

    const int NB  = (N + 1023) / 1024;
    const int NBZ = (N * 16 + 1023) / 1024;
    const int Bh1 = (N + 63) / 64;

    hipLaunchKernelGGL(ksetup, dim3(65 + NBZ), dim3(256), 0, stream,
                       W1, W2, ats2, atd2, w1fh, w1fl, u, v, w2tb, degR, N);
    hipLaunchKernelGGL(mega1, dim3(Bh1), dim3(256), 0, stream,
                       x, w1fh, w1fl, ats1, atd1, h1b, as1, ad1, N,
                       ei, degR, rank, E, Bh1);
    hipLaunchKernelGGL(kscan1, dim3(NB), dim3(256), 0, stream,
                       degR, rowptr, bsum, N);
    hipLaunchKernelGGL(kscan2, dim3(1), dim3(128), 0, stream, bsum, NB);
    hipLaunchKernelGGL(kscat, dim3((E + 255) / 256), dim3(256), 0, stream,
                       ei, rowptr, bsum, rank, degR, colidx, E);
    hipLaunchKernelGGL(kg1, dim3((N + 3) / 4), dim3(256), 0, stream,
                       rowptr, bsum, colidx, h1b, as1, ad1, b1, u, v,
                       x2b, as2, ad2, N, E);
    hipLaunchKernelGGL(kh2, dim3((N + 63) / 64), dim3(256), 0, stream,
                       x2b, w2tb, h2b, N);
    hipLaunchKernelGGL(kg2, dim3((N + 3) / 4), dim3(256), 0, stream,
                       rowptr, bsum, colidx, h2b, as2, ad2, b2, out, N, E);
}